// Round 1
// baseline (3090.238 us; speedup 1.0000x reference)
//
#include <hip/hip_runtime.h>
#include <math.h>

#define EPS_BN 1e-5f

// ---------------- degree ----------------
__global__ __launch_bounds__(256) void count_deg_k(const int* __restrict__ dst,
                                                   float* __restrict__ deg, int nE) {
    int e = blockIdx.x * 256 + threadIdx.x;
    if (e < nE) atomicAdd(&deg[dst[e]], 1.0f);
}

__global__ __launch_bounds__(256) void dinv_k(float* __restrict__ deg, int n) {
    int i = blockIdx.x * 256 + threadIdx.x;
    if (i < n) deg[i] = rsqrtf(deg[i] + 1.0f);  // +1 = self loop
}

// ---------------- scatter-add conv ----------------
// one 64-lane wave per edge; each lane moves a float2 (128 floats/row)
__global__ __launch_bounds__(256) void scatter_k(const float* __restrict__ h,
                                                 const int* __restrict__ src,
                                                 const int* __restrict__ dst,
                                                 const float* __restrict__ dinv,
                                                 float* __restrict__ out, int nE) {
    int gtid = blockIdx.x * 256 + threadIdx.x;
    int e = gtid >> 6;
    if (e >= nE) return;
    int j = threadIdx.x & 63;
    int s = src[e];
    int d = dst[e];
    float norm = dinv[s] * dinv[d];
    float2 v = *(const float2*)&h[s * 128 + j * 2];
    float* o = out + d * 128 + j * 2;
    atomicAdd(o, v.x * norm);
    atomicAdd(o + 1, v.y * norm);
}

// ---------------- conv epilogue: += selfloop + bias, BN, ReLU ----------------
__global__ __launch_bounds__(256) void conv_epi_k(float* __restrict__ out,
                                                  const float* __restrict__ h,
                                                  const float* __restrict__ dinv,
                                                  const float* __restrict__ bias,
                                                  const float* __restrict__ g,
                                                  const float* __restrict__ be,
                                                  const float* __restrict__ mn,
                                                  const float* __restrict__ vr, int n) {
    int idx = blockIdx.x * 256 + threadIdx.x;  // over n*32 (float4 each)
    if (idx >= n * 32) return;
    int node = idx >> 5;
    int c = (idx & 31) * 4;
    float di = dinv[node];
    float sl = di * di;
    float4 o = *(float4*)&out[node * 128 + c];
    float4 hv = *(const float4*)&h[node * 128 + c];
    float ov[4] = {o.x, o.y, o.z, o.w};
    float hh[4] = {hv.x, hv.y, hv.z, hv.w};
#pragma unroll
    for (int i = 0; i < 4; i++) {
        float sc = g[c + i] * rsqrtf(vr[c + i] + EPS_BN);
        float v = ov[i] + hh[i] * sl + bias[c + i];
        v = (v - mn[c + i]) * sc + be[c + i];
        ov[i] = fmaxf(v, 0.0f);
    }
    float4 r = {ov[0], ov[1], ov[2], ov[3]};
    *(float4*)&out[node * 128 + c] = r;
}

// ---------------- f32 GEMM: Y = X(n,128) @ W(128,128), fused epilogues ----------------
// MODE 0: raw   MODE 1: relu(bn(v + bias))   MODE 2: relu(v + bias)
template <int MODE>
__global__ __launch_bounds__(256) void gemm128_k(const float* __restrict__ X,
                                                 const float* __restrict__ W,
                                                 const float* __restrict__ bias,
                                                 const float* __restrict__ g,
                                                 const float* __restrict__ be,
                                                 const float* __restrict__ mn,
                                                 const float* __restrict__ vr,
                                                 float* __restrict__ Y, int nrows) {
    __shared__ float sX[64][36];    // 64 rows x 32 k-chunk, pad 36 (bank spread)
    __shared__ float sW[32][128];   // k-chunk x 128 cols
    const int tid = threadIdx.x;
    const int row0 = blockIdx.x * 64;
    const int tx = tid & 31, ty = tid >> 5;
    const int r0 = ty * 8, c0 = tx * 4;
    float acc[8][4];
#pragma unroll
    for (int i = 0; i < 8; i++)
#pragma unroll
        for (int j = 0; j < 4; j++) acc[i][j] = 0.0f;

    for (int kc = 0; kc < 128; kc += 32) {
#pragma unroll
        for (int i = 0; i < 2; i++) {
            int idx = tid + i * 256;      // 0..511
            int r = idx >> 3;             // 0..63
            int kq = (idx & 7) * 4;       // 0..28
            int rg = row0 + r;
            if (rg >= nrows) rg = nrows - 1;
            *(float4*)&sX[r][kq] = *(const float4*)&X[rg * 128 + kc + kq];
        }
#pragma unroll
        for (int i = 0; i < 4; i++) {
            int idx = tid + i * 256;      // 0..1023
            int kr = idx >> 5;            // 0..31
            int cq = (idx & 31) * 4;
            *(float4*)&sW[kr][cq] = *(const float4*)&W[(kc + kr) * 128 + cq];
        }
        __syncthreads();
#pragma unroll
        for (int k = 0; k < 32; k += 4) {
            float4 w[4], a[8];
#pragma unroll
            for (int j = 0; j < 4; j++) w[j] = *(float4*)&sW[k + j][c0];
#pragma unroll
            for (int i = 0; i < 8; i++) a[i] = *(float4*)&sX[r0 + i][k];
#pragma unroll
            for (int i = 0; i < 8; i++) {
                float av[4] = {a[i].x, a[i].y, a[i].z, a[i].w};
#pragma unroll
                for (int j = 0; j < 4; j++) {
                    acc[i][0] = fmaf(av[j], w[j].x, acc[i][0]);
                    acc[i][1] = fmaf(av[j], w[j].y, acc[i][1]);
                    acc[i][2] = fmaf(av[j], w[j].z, acc[i][2]);
                    acc[i][3] = fmaf(av[j], w[j].w, acc[i][3]);
                }
            }
        }
        __syncthreads();
    }

    // epilogue: v*pscale + pshift (+relu)
    float pscale[4], pshift[4];
#pragma unroll
    for (int j = 0; j < 4; j++) {
        if (MODE == 1) {
            float sc = g[c0 + j] * rsqrtf(vr[c0 + j] + EPS_BN);
            pscale[j] = sc;
            pshift[j] = be[c0 + j] + (bias[c0 + j] - mn[c0 + j]) * sc;
        } else if (MODE == 2) {
            pscale[j] = 1.0f;
            pshift[j] = bias[c0 + j];
        } else {
            pscale[j] = 1.0f;
            pshift[j] = 0.0f;
        }
    }
#pragma unroll
    for (int i = 0; i < 8; i++) {
        int rg = row0 + r0 + i;
        if (rg < nrows) {
            float4 o;
            float v0 = acc[i][0] * pscale[0] + pshift[0];
            float v1 = acc[i][1] * pscale[1] + pshift[1];
            float v2 = acc[i][2] * pscale[2] + pshift[2];
            float v3 = acc[i][3] * pscale[3] + pshift[3];
            if (MODE != 0) {
                v0 = fmaxf(v0, 0.0f); v1 = fmaxf(v1, 0.0f);
                v2 = fmaxf(v2, 0.0f); v3 = fmaxf(v3, 0.0f);
            }
            o.x = v0; o.y = v1; o.z = v2; o.w = v3;
            *(float4*)&Y[rg * 128 + c0] = o;
        }
    }
}

// ---------------- head: softplus(h1 @ Wo + bo) ----------------
__global__ __launch_bounds__(256) void head_k(const float* __restrict__ h1,
                                              const float* __restrict__ Wo,
                                              const float* __restrict__ bo,
                                              float* __restrict__ out, int n) {
    int gtid = blockIdx.x * 256 + threadIdx.x;
    int node = gtid >> 6;
    if (node >= n) return;
    int lane = threadIdx.x & 63;
    float2 hv = *(const float2*)&h1[node * 128 + lane * 2];
    float2 wv = *(const float2*)&Wo[lane * 2];
    float p = hv.x * wv.x + hv.y * wv.y;
#pragma unroll
    for (int off = 32; off > 0; off >>= 1) p += __shfl_down(p, off, 64);
    if (lane == 0) {
        float x = p + bo[0];
        // stable softplus
        out[node] = fmaxf(x, 0.0f) + log1pf(expf(-fabsf(x)));
    }
}

extern "C" void kernel_launch(void* const* d_in, const int* in_sizes, int n_in,
                              void* d_out, int out_size, void* d_ws, size_t ws_size,
                              hipStream_t stream) {
    const float* x = (const float*)d_in[0];
    const int* ei = (const int*)d_in[1];
    const int N = in_sizes[0] / 128;
    const int E = in_sizes[1] / 2;
    const int* srcv = ei;
    const int* dstv = ei + E;
    const float* W1 = (const float*)d_in[2];  const float* b1 = (const float*)d_in[3];
    const float* W2 = (const float*)d_in[4];  const float* b2 = (const float*)d_in[5];
    const float* Wf1 = (const float*)d_in[6]; const float* bf1 = (const float*)d_in[7];
    const float* Wf2 = (const float*)d_in[8]; const float* bf2 = (const float*)d_in[9];
    const float* Wo = (const float*)d_in[10]; const float* bo = (const float*)d_in[11];
    const float* g1 = (const float*)d_in[12], *be1 = (const float*)d_in[13],
               *m1 = (const float*)d_in[14], *v1 = (const float*)d_in[15];
    const float* g2 = (const float*)d_in[16], *be2 = (const float*)d_in[17],
               *m2 = (const float*)d_in[18], *v2 = (const float*)d_in[19];
    const float* g3 = (const float*)d_in[20], *be3 = (const float*)d_in[21],
               *m3 = (const float*)d_in[22], *v3 = (const float*)d_in[23];

    char* ws = (char*)d_ws;
    float* dinv = (float*)ws;  // N floats (deg then dinv in place)
    size_t off = (((size_t)N * 4) + 255) & ~(size_t)255;
    float* bufA = (float*)(ws + off);
    float* bufB = (float*)(ws + off + (size_t)N * 128 * 4);

    float* out_pred = (float*)d_out;
    float* out_h1 = out_pred + N;

    const size_t featBytes = (size_t)N * 128 * 4;
    const int gblocks = (N + 63) / 64;
    const int eblocks = (E + 255) / 256;
    const int nblocks = (N + 255) / 256;
    const int sblocks = (int)(((size_t)E * 64 + 255) / 256);
    const int pblocks = (int)(((size_t)N * 32 + 255) / 256);
    const int hblocks = (int)(((size_t)N * 64 + 255) / 256);

    // degree / dinv
    hipMemsetAsync(dinv, 0, (size_t)N * 4, stream);
    hipMemsetAsync(bufB, 0, featBytes, stream);
    count_deg_k<<<eblocks, 256, 0, stream>>>(dstv, dinv, E);
    dinv_k<<<nblocks, 256, 0, stream>>>(dinv, N);

    // layer 1: h = relu(bn1(conv(x@W1) + b1))
    gemm128_k<0><<<gblocks, 256, 0, stream>>>(x, W1, nullptr, nullptr, nullptr, nullptr,
                                              nullptr, bufA, N);
    scatter_k<<<sblocks, 256, 0, stream>>>(bufA, srcv, dstv, dinv, bufB, E);
    conv_epi_k<<<pblocks, 256, 0, stream>>>(bufB, bufA, dinv, b1, g1, be1, m1, v1, N);

    // layer 2: h = relu(bn2(conv(h@W2) + b2))
    gemm128_k<0><<<gblocks, 256, 0, stream>>>(bufB, W2, nullptr, nullptr, nullptr, nullptr,
                                              nullptr, bufA, N);
    hipMemsetAsync(bufB, 0, featBytes, stream);
    scatter_k<<<sblocks, 256, 0, stream>>>(bufA, srcv, dstv, dinv, bufB, E);
    conv_epi_k<<<pblocks, 256, 0, stream>>>(bufB, bufA, dinv, b2, g2, be2, m2, v2, N);

    // layer 3: h = relu(bn3(h@Wf1 + bf1))
    gemm128_k<1><<<gblocks, 256, 0, stream>>>(bufB, Wf1, bf1, g3, be3, m3, v3, bufA, N);

    // layer 4: h1 = relu(h@Wf2 + bf2) -> straight into d_out
    gemm128_k<2><<<gblocks, 256, 0, stream>>>(bufA, Wf2, bf2, nullptr, nullptr, nullptr,
                                              nullptr, out_h1, N);

    // head: raw_pred = softplus(h1@Wo + bo)
    head_k<<<hblocks, 256, 0, stream>>>(out_h1, Wo, bo, out_pred, N);
}

// Round 2
// 822.572 us; speedup vs baseline: 3.7568x; 3.7568x over previous
//
#include <hip/hip_runtime.h>
#include <math.h>

#define EPS_BN 1e-5f

// ================= CSR build =================
__global__ __launch_bounds__(256) void hist_k(const int* __restrict__ dst,
                                              int* __restrict__ cnt, int nE) {
    int e = blockIdx.x * 256 + threadIdx.x;
    if (e < nE) atomicAdd(&cnt[dst[e]], 1);
}

// per-block sums of cnt
__global__ __launch_bounds__(256) void scan1_k(const int* __restrict__ cnt,
                                               int* __restrict__ bsum, int n) {
    __shared__ int s[256];
    int i = blockIdx.x * 256 + threadIdx.x;
    int t = threadIdx.x;
    s[t] = (i < n) ? cnt[i] : 0;
    __syncthreads();
    for (int off = 128; off > 0; off >>= 1) {
        if (t < off) s[t] += s[t + off];
        __syncthreads();
    }
    if (t == 0) bsum[blockIdx.x] = s[0];
}

// exclusive scan of block sums (nb <= 1024), single block of 1024
__global__ __launch_bounds__(1024) void scan2_k(int* __restrict__ bsum, int nb) {
    __shared__ int s[1024];
    int t = threadIdx.x;
    s[t] = (t < nb) ? bsum[t] : 0;
    __syncthreads();
    for (int off = 1; off < 1024; off <<= 1) {
        int v = (t >= off) ? s[t - off] : 0;
        __syncthreads();
        s[t] += v;
        __syncthreads();
    }
    if (t < nb) bsum[t] = (t == 0) ? 0 : s[t - 1];
}

// per-block exclusive scan + block offset -> rowstart, cursor
__global__ __launch_bounds__(256) void scan3_k(const int* __restrict__ cnt,
                                               const int* __restrict__ bsum,
                                               int* __restrict__ rowstart,
                                               int* __restrict__ cursor, int n, int nE) {
    __shared__ int s[256];
    int i = blockIdx.x * 256 + threadIdx.x;
    int t = threadIdx.x;
    s[t] = (i < n) ? cnt[i] : 0;
    __syncthreads();
    for (int off = 1; off < 256; off <<= 1) {
        int v = (t >= off) ? s[t - off] : 0;
        __syncthreads();
        s[t] += v;
        __syncthreads();
    }
    int excl = bsum[blockIdx.x] + ((t == 0) ? 0 : s[t - 1]);
    if (i < n) {
        rowstart[i] = excl;
        cursor[i] = excl;
    }
    if (i == 0) rowstart[n] = nE;
}

__global__ __launch_bounds__(256) void fill_k(const int* __restrict__ src,
                                              const int* __restrict__ dst,
                                              int* __restrict__ cursor,
                                              int* __restrict__ col, int nE) {
    int e = blockIdx.x * 256 + threadIdx.x;
    if (e < nE) {
        int p = atomicAdd(&cursor[dst[e]], 1);
        col[p] = src[e];
    }
}

__global__ __launch_bounds__(256) void dinv_k(const int* __restrict__ cnt,
                                              float* __restrict__ dinv, int n) {
    int i = blockIdx.x * 256 + threadIdx.x;
    if (i < n) dinv[i] = rsqrtf((float)cnt[i] + 1.0f);  // +1 = self loop
}

// ============ gather conv: out = relu(bn(sum + selfloop + bias)) ============
// one 64-lane wave per dst node; lane handles 2 channels (float2)
__global__ __launch_bounds__(256) void gather_k(const float* __restrict__ h,
                                                const int* __restrict__ rowstart,
                                                const int* __restrict__ col,
                                                const float* __restrict__ dinv,
                                                const float* __restrict__ bias,
                                                const float* __restrict__ g,
                                                const float* __restrict__ be,
                                                const float* __restrict__ mn,
                                                const float* __restrict__ vr,
                                                float* __restrict__ out, int n) {
    int node = blockIdx.x * 4 + (threadIdx.x >> 6);
    if (node >= n) return;
    int lane = threadIdx.x & 63;
    int c = lane * 2;
    int beg = rowstart[node], end = rowstart[node + 1];
    float dd = dinv[node];
    float2 hv = *(const float2*)&h[(size_t)node * 128 + c];
    float acc0 = hv.x * dd * dd, acc1 = hv.y * dd * dd;  // self loop
    int p = beg;
    for (; p + 1 < end; p += 2) {
        int s0 = col[p], s1 = col[p + 1];
        float n0 = dinv[s0] * dd, n1 = dinv[s1] * dd;
        float2 a = *(const float2*)&h[(size_t)s0 * 128 + c];
        float2 b = *(const float2*)&h[(size_t)s1 * 128 + c];
        acc0 = fmaf(a.x, n0, acc0);
        acc1 = fmaf(a.y, n0, acc1);
        acc0 = fmaf(b.x, n1, acc0);
        acc1 = fmaf(b.y, n1, acc1);
    }
    if (p < end) {
        int s0 = col[p];
        float n0 = dinv[s0] * dd;
        float2 a = *(const float2*)&h[(size_t)s0 * 128 + c];
        acc0 = fmaf(a.x, n0, acc0);
        acc1 = fmaf(a.y, n0, acc1);
    }
    float sc0 = g[c] * rsqrtf(vr[c] + EPS_BN);
    float sc1 = g[c + 1] * rsqrtf(vr[c + 1] + EPS_BN);
    float o0 = (acc0 + bias[c] - mn[c]) * sc0 + be[c];
    float o1 = (acc1 + bias[c + 1] - mn[c + 1]) * sc1 + be[c + 1];
    float2 r = {fmaxf(o0, 0.0f), fmaxf(o1, 0.0f)};
    *(float2*)&out[(size_t)node * 128 + c] = r;
}

// ---------------- f32 GEMM: Y = X(n,128) @ W(128,128), fused epilogues ----------------
// MODE 0: raw   MODE 1: relu(bn(v + bias))   MODE 2: relu(v + bias)
template <int MODE>
__global__ __launch_bounds__(256) void gemm128_k(const float* __restrict__ X,
                                                 const float* __restrict__ W,
                                                 const float* __restrict__ bias,
                                                 const float* __restrict__ g,
                                                 const float* __restrict__ be,
                                                 const float* __restrict__ mn,
                                                 const float* __restrict__ vr,
                                                 float* __restrict__ Y, int nrows) {
    __shared__ float sX[64][36];
    __shared__ float sW[32][128];
    const int tid = threadIdx.x;
    const int row0 = blockIdx.x * 64;
    const int tx = tid & 31, ty = tid >> 5;
    const int r0 = ty * 8, c0 = tx * 4;
    float acc[8][4];
#pragma unroll
    for (int i = 0; i < 8; i++)
#pragma unroll
        for (int j = 0; j < 4; j++) acc[i][j] = 0.0f;

    for (int kc = 0; kc < 128; kc += 32) {
#pragma unroll
        for (int i = 0; i < 2; i++) {
            int idx = tid + i * 256;
            int r = idx >> 3;
            int kq = (idx & 7) * 4;
            int rg = row0 + r;
            if (rg >= nrows) rg = nrows - 1;
            *(float4*)&sX[r][kq] = *(const float4*)&X[(size_t)rg * 128 + kc + kq];
        }
#pragma unroll
        for (int i = 0; i < 4; i++) {
            int idx = tid + i * 256;
            int kr = idx >> 5;
            int cq = (idx & 31) * 4;
            *(float4*)&sW[kr][cq] = *(const float4*)&W[(size_t)(kc + kr) * 128 + cq];
        }
        __syncthreads();
#pragma unroll
        for (int k = 0; k < 32; k += 4) {
            float4 w[4], a[8];
#pragma unroll
            for (int j = 0; j < 4; j++) w[j] = *(float4*)&sW[k + j][c0];
#pragma unroll
            for (int i = 0; i < 8; i++) a[i] = *(float4*)&sX[r0 + i][k];
#pragma unroll
            for (int i = 0; i < 8; i++) {
                float av[4] = {a[i].x, a[i].y, a[i].z, a[i].w};
#pragma unroll
                for (int j = 0; j < 4; j++) {
                    acc[i][0] = fmaf(av[j], w[j].x, acc[i][0]);
                    acc[i][1] = fmaf(av[j], w[j].y, acc[i][1]);
                    acc[i][2] = fmaf(av[j], w[j].z, acc[i][2]);
                    acc[i][3] = fmaf(av[j], w[j].w, acc[i][3]);
                }
            }
        }
        __syncthreads();
    }

    float pscale[4], pshift[4];
#pragma unroll
    for (int j = 0; j < 4; j++) {
        if (MODE == 1) {
            float sc = g[c0 + j] * rsqrtf(vr[c0 + j] + EPS_BN);
            pscale[j] = sc;
            pshift[j] = be[c0 + j] + (bias[c0 + j] - mn[c0 + j]) * sc;
        } else if (MODE == 2) {
            pscale[j] = 1.0f;
            pshift[j] = bias[c0 + j];
        } else {
            pscale[j] = 1.0f;
            pshift[j] = 0.0f;
        }
    }
#pragma unroll
    for (int i = 0; i < 8; i++) {
        int rg = row0 + r0 + i;
        if (rg < nrows) {
            float4 o;
            float v0 = acc[i][0] * pscale[0] + pshift[0];
            float v1 = acc[i][1] * pscale[1] + pshift[1];
            float v2 = acc[i][2] * pscale[2] + pshift[2];
            float v3 = acc[i][3] * pscale[3] + pshift[3];
            if (MODE != 0) {
                v0 = fmaxf(v0, 0.0f); v1 = fmaxf(v1, 0.0f);
                v2 = fmaxf(v2, 0.0f); v3 = fmaxf(v3, 0.0f);
            }
            o.x = v0; o.y = v1; o.z = v2; o.w = v3;
            *(float4*)&Y[(size_t)rg * 128 + c0] = o;
        }
    }
}

// ---------------- head: softplus(h1 @ Wo + bo) ----------------
__global__ __launch_bounds__(256) void head_k(const float* __restrict__ h1,
                                              const float* __restrict__ Wo,
                                              const float* __restrict__ bo,
                                              float* __restrict__ out, int n) {
    int gtid = blockIdx.x * 256 + threadIdx.x;
    int node = gtid >> 6;
    if (node >= n) return;
    int lane = threadIdx.x & 63;
    float2 hv = *(const float2*)&h1[(size_t)node * 128 + lane * 2];
    float2 wv = *(const float2*)&Wo[lane * 2];
    float p = hv.x * wv.x + hv.y * wv.y;
#pragma unroll
    for (int off = 32; off > 0; off >>= 1) p += __shfl_down(p, off, 64);
    if (lane == 0) {
        float x = p + bo[0];
        out[node] = fmaxf(x, 0.0f) + log1pf(expf(-fabsf(x)));
    }
}

extern "C" void kernel_launch(void* const* d_in, const int* in_sizes, int n_in,
                              void* d_out, int out_size, void* d_ws, size_t ws_size,
                              hipStream_t stream) {
    const float* x = (const float*)d_in[0];
    const int* ei = (const int*)d_in[1];
    const int N = in_sizes[0] / 128;
    const int E = in_sizes[1] / 2;
    const int* srcv = ei;
    const int* dstv = ei + E;
    const float* W1 = (const float*)d_in[2];  const float* b1 = (const float*)d_in[3];
    const float* W2 = (const float*)d_in[4];  const float* b2 = (const float*)d_in[5];
    const float* Wf1 = (const float*)d_in[6]; const float* bf1 = (const float*)d_in[7];
    const float* Wf2 = (const float*)d_in[8]; const float* bf2 = (const float*)d_in[9];
    const float* Wo = (const float*)d_in[10]; const float* bo = (const float*)d_in[11];
    const float* g1 = (const float*)d_in[12], *be1 = (const float*)d_in[13],
               *m1 = (const float*)d_in[14], *v1 = (const float*)d_in[15];
    const float* g2 = (const float*)d_in[16], *be2 = (const float*)d_in[17],
               *m2 = (const float*)d_in[18], *v2 = (const float*)d_in[19];
    const float* g3 = (const float*)d_in[20], *be3 = (const float*)d_in[21],
               *m3 = (const float*)d_in[22], *v3 = (const float*)d_in[23];

    // ---- workspace carve-up ----
    char* ws = (char*)d_ws;
    size_t off = 0;
    auto carve = [&](size_t bytes) {
        char* p = ws + off;
        off = (off + bytes + 255) & ~(size_t)255;
        return p;
    };
    int nb = (N + 255) / 256;
    int* cnt = (int*)carve((size_t)N * 4);
    int* bsum = (int*)carve((size_t)((nb + 1023) & ~1023) * 4);
    int* rowstart = (int*)carve((size_t)(N + 1) * 4);
    int* cursor = (int*)carve((size_t)N * 4);
    int* col = (int*)carve((size_t)E * 4);
    float* dinv = (float*)carve((size_t)N * 4);
    float* bufA = (float*)carve((size_t)N * 128 * 4);
    float* bufB = (float*)carve((size_t)N * 128 * 4);

    float* out_pred = (float*)d_out;
    float* out_h1 = out_pred + N;

    const int gblocks = (N + 63) / 64;
    const int eblocks = (E + 255) / 256;
    const int nblocks = nb;
    const int wblocks = (N + 3) / 4;  // 4 waves/block, 1 wave/node
    const int hblocks = (int)(((size_t)N * 64 + 255) / 256);

    // ---- CSR build (per call; ws is re-poisoned by harness) ----
    hipMemsetAsync(cnt, 0, (size_t)N * 4, stream);
    hist_k<<<eblocks, 256, 0, stream>>>(dstv, cnt, E);
    scan1_k<<<nblocks, 256, 0, stream>>>(cnt, bsum, N);
    scan2_k<<<1, 1024, 0, stream>>>(bsum, nblocks);
    scan3_k<<<nblocks, 256, 0, stream>>>(cnt, bsum, rowstart, cursor, N, E);
    fill_k<<<eblocks, 256, 0, stream>>>(srcv, dstv, cursor, col, E);
    dinv_k<<<nblocks, 256, 0, stream>>>(cnt, dinv, N);

    // layer 1: h = relu(bn1(conv(x@W1) + b1))
    gemm128_k<0><<<gblocks, 256, 0, stream>>>(x, W1, nullptr, nullptr, nullptr, nullptr,
                                              nullptr, bufA, N);
    gather_k<<<wblocks, 256, 0, stream>>>(bufA, rowstart, col, dinv, b1, g1, be1, m1, v1,
                                          bufB, N);

    // layer 2: h = relu(bn2(conv(h@W2) + b2))
    gemm128_k<0><<<gblocks, 256, 0, stream>>>(bufB, W2, nullptr, nullptr, nullptr, nullptr,
                                              nullptr, bufA, N);
    gather_k<<<wblocks, 256, 0, stream>>>(bufA, rowstart, col, dinv, b2, g2, be2, m2, v2,
                                          bufB, N);

    // layer 3: h = relu(bn3(h@Wf1 + bf1))
    gemm128_k<1><<<gblocks, 256, 0, stream>>>(bufB, Wf1, bf1, g3, be3, m3, v3, bufA, N);

    // layer 4: h1 = relu(h@Wf2 + bf2) -> straight into d_out
    gemm128_k<2><<<gblocks, 256, 0, stream>>>(bufA, Wf2, bf2, nullptr, nullptr, nullptr,
                                              nullptr, out_h1, N);

    // head: raw_pred = softplus(h1@Wo + bo)
    head_k<<<hblocks, 256, 0, stream>>>(out_h1, Wo, bo, out_pred, N);
}

// Round 3
// 640.936 us; speedup vs baseline: 4.8214x; 1.2834x over previous
//
#include <hip/hip_runtime.h>
#include <math.h>

#define EPS_BN 1e-5f

typedef __attribute__((ext_vector_type(8))) short bf16x8;
typedef __attribute__((ext_vector_type(4))) float f32x4;

__device__ __forceinline__ ushort f2bf(float f) {
    uint u = __float_as_uint(f);
    u += 0x7FFF + ((u >> 16) & 1);  // RTN-even
    return (ushort)(u >> 16);
}
__device__ __forceinline__ float bf2f(uint h) {
    return __uint_as_float(h << 16);
}

// ================= CSR build =================
__global__ __launch_bounds__(256) void hist_k(const int* __restrict__ dst,
                                              int* __restrict__ cnt, int nE) {
    int e = blockIdx.x * 256 + threadIdx.x;
    if (e < nE) atomicAdd(&cnt[dst[e]], 1);
}

__global__ __launch_bounds__(256) void scan1_k(const int* __restrict__ cnt,
                                               int* __restrict__ bsum, int n) {
    __shared__ int s[256];
    int i = blockIdx.x * 256 + threadIdx.x;
    int t = threadIdx.x;
    s[t] = (i < n) ? cnt[i] : 0;
    __syncthreads();
    for (int off = 128; off > 0; off >>= 1) {
        if (t < off) s[t] += s[t + off];
        __syncthreads();
    }
    if (t == 0) bsum[blockIdx.x] = s[0];
}

__global__ __launch_bounds__(1024) void scan2_k(int* __restrict__ bsum, int nb) {
    __shared__ int s[1024];
    int t = threadIdx.x;
    s[t] = (t < nb) ? bsum[t] : 0;
    __syncthreads();
    for (int off = 1; off < 1024; off <<= 1) {
        int v = (t >= off) ? s[t - off] : 0;
        __syncthreads();
        s[t] += v;
        __syncthreads();
    }
    if (t < nb) bsum[t] = (t == 0) ? 0 : s[t - 1];
}

__global__ __launch_bounds__(256) void scan3_k(const int* __restrict__ cnt,
                                               const int* __restrict__ bsum,
                                               int* __restrict__ rowstart,
                                               int* __restrict__ cursor, int n, int nE) {
    __shared__ int s[256];
    int i = blockIdx.x * 256 + threadIdx.x;
    int t = threadIdx.x;
    s[t] = (i < n) ? cnt[i] : 0;
    __syncthreads();
    for (int off = 1; off < 256; off <<= 1) {
        int v = (t >= off) ? s[t - off] : 0;
        __syncthreads();
        s[t] += v;
        __syncthreads();
    }
    int excl = bsum[blockIdx.x] + ((t == 0) ? 0 : s[t - 1]);
    if (i < n) {
        rowstart[i] = excl;
        cursor[i] = excl;
    }
    if (i == 0) rowstart[n] = nE;
}

__global__ __launch_bounds__(256) void fill_k(const int* __restrict__ src,
                                              const int* __restrict__ dst,
                                              int* __restrict__ cursor,
                                              int* __restrict__ col, int nE) {
    int e = blockIdx.x * 256 + threadIdx.x;
    if (e < nE) {
        int p = atomicAdd(&cursor[dst[e]], 1);
        col[p] = src[e];
    }
}

__global__ __launch_bounds__(256) void dinv_k(const int* __restrict__ cnt,
                                              float* __restrict__ dinv, int n) {
    int i = blockIdx.x * 256 + threadIdx.x;
    if (i < n) dinv[i] = rsqrtf((float)cnt[i] + 1.0f);  // +1 = self loop
}

// ================= dtype prep =================
// x f32 -> bf16 (4 elems/thread)
__global__ __launch_bounds__(256) void cvt_bf16_k(const float* __restrict__ x,
                                                  ushort* __restrict__ xb, int n4) {
    int i = blockIdx.x * 256 + threadIdx.x;
    if (i >= n4) return;
    float4 v = *(const float4*)&x[(size_t)i * 4];
    ushort4 o = {f2bf(v.x), f2bf(v.y), f2bf(v.z), f2bf(v.w)};
    *(ushort4*)&xb[(size_t)i * 4] = o;
}

// W (k x n, f32) -> Wt (n x k, bf16)
__global__ __launch_bounds__(256) void prep_wt_k(const float* __restrict__ W,
                                                 ushort* __restrict__ Wt) {
    int i = blockIdx.x * 256 + threadIdx.x;  // < 16384
    int n = i >> 7, k = i & 127;
    Wt[n * 128 + k] = f2bf(W[k * 128 + n]);
}

// ============ gather conv (bf16 in / bf16 out): relu(bn(sum + selfloop + bias)) ============
__global__ __launch_bounds__(256) void gather_k(const ushort* __restrict__ h,
                                                const int* __restrict__ rowstart,
                                                const int* __restrict__ col,
                                                const float* __restrict__ dinv,
                                                const float* __restrict__ bias,
                                                const float* __restrict__ g,
                                                const float* __restrict__ be,
                                                const float* __restrict__ mn,
                                                const float* __restrict__ vr,
                                                ushort* __restrict__ out, int n) {
    int node = blockIdx.x * 4 + (threadIdx.x >> 6);
    if (node >= n) return;
    int lane = threadIdx.x & 63;
    int c = lane * 2;
    int beg = rowstart[node], end = rowstart[node + 1];
    float dd = dinv[node];
    uint hp = *(const uint*)&h[(size_t)node * 128 + c];
    float acc0 = bf2f(hp & 0xffffu) * dd * dd;  // self loop
    float acc1 = bf2f(hp >> 16) * dd * dd;
    int p = beg;
    for (; p + 1 < end; p += 2) {
        int s0 = col[p], s1 = col[p + 1];
        float n0 = dinv[s0] * dd, n1 = dinv[s1] * dd;
        uint a = *(const uint*)&h[(size_t)s0 * 128 + c];
        uint b = *(const uint*)&h[(size_t)s1 * 128 + c];
        acc0 = fmaf(bf2f(a & 0xffffu), n0, acc0);
        acc1 = fmaf(bf2f(a >> 16), n0, acc1);
        acc0 = fmaf(bf2f(b & 0xffffu), n1, acc0);
        acc1 = fmaf(bf2f(b >> 16), n1, acc1);
    }
    if (p < end) {
        int s0 = col[p];
        float n0 = dinv[s0] * dd;
        uint a = *(const uint*)&h[(size_t)s0 * 128 + c];
        acc0 = fmaf(bf2f(a & 0xffffu), n0, acc0);
        acc1 = fmaf(bf2f(a >> 16), n0, acc1);
    }
    float sc0 = g[c] * rsqrtf(vr[c] + EPS_BN);
    float sc1 = g[c + 1] * rsqrtf(vr[c + 1] + EPS_BN);
    float o0 = fmaxf((acc0 + bias[c] - mn[c]) * sc0 + be[c], 0.0f);
    float o1 = fmaxf((acc1 + bias[c + 1] - mn[c + 1]) * sc1 + be[c + 1], 0.0f);
    uint r = (uint)f2bf(o0) | ((uint)f2bf(o1) << 16);
    *(uint*)&out[(size_t)node * 128 + c] = r;
}

// ============ MFMA GEMM: Y = X(n,128) @ W(128,128), fused epilogues ============
// MODE 0: raw -> bf16   MODE 1: relu(bn(v+bias)) -> bf16   MODE 2: relu(v+bias) -> f32
// block: 256 thr (4 waves); tile 64 rows x 128 cols; K=128 single pass.
template <int MODE>
__global__ __launch_bounds__(256) void mfma_gemm_k(const ushort* __restrict__ Xb,
                                                   const ushort* __restrict__ Wt,
                                                   const float* __restrict__ bias,
                                                   const float* __restrict__ g,
                                                   const float* __restrict__ be,
                                                   const float* __restrict__ mn,
                                                   const float* __restrict__ vr,
                                                   void* __restrict__ Y, int nrows) {
    constexpr int LDK = 136;           // 128 + 8 pad (16B), kills pow2 bank stride
    __shared__ ushort sX[64 * LDK];    // 17 KB
    __shared__ ushort sW[128 * LDK];   // 34 KB
    const int tid = threadIdx.x;
    const int row0 = blockIdx.x * 64;

    // stage Wt (128 rows x 128 bf16): 2048 16B-chunks, 8/thread
#pragma unroll
    for (int i = 0; i < 8; i++) {
        int c = tid + i * 256;
        int r = c >> 4, o = c & 15;
        *(int4*)&sW[r * LDK + o * 8] = *(const int4*)&Wt[r * 128 + o * 8];
    }
    // stage X (64 rows x 128 bf16): 1024 chunks, 4/thread
#pragma unroll
    for (int i = 0; i < 4; i++) {
        int c = tid + i * 256;
        int r = c >> 4, o = c & 15;
        int rg = row0 + r;
        if (rg >= nrows) rg = nrows - 1;
        *(int4*)&sX[r * LDK + o * 8] = *(const int4*)&Xb[(size_t)rg * 128 + o * 8];
    }
    __syncthreads();

    const int wave = tid >> 6, lane = tid & 63;
    const int rw = (wave >> 1) * 32;   // wave row base: 0 / 32
    const int cw = (wave & 1) * 64;    // wave col base: 0 / 64
    const int lm = lane & 15, lq = lane >> 4;

    f32x4 acc[2][4];
#pragma unroll
    for (int tr = 0; tr < 2; tr++)
#pragma unroll
        for (int tc = 0; tc < 4; tc++) acc[tr][tc] = (f32x4){0.f, 0.f, 0.f, 0.f};

#pragma unroll
    for (int ks = 0; ks < 4; ks++) {
        int kb = ks * 32 + lq * 8;
        bf16x8 a[2], b[4];
#pragma unroll
        for (int tr = 0; tr < 2; tr++)
            a[tr] = *(bf16x8*)&sX[(rw + tr * 16 + lm) * LDK + kb];
#pragma unroll
        for (int tc = 0; tc < 4; tc++)
            b[tc] = *(bf16x8*)&sW[(cw + tc * 16 + lm) * LDK + kb];
#pragma unroll
        for (int tr = 0; tr < 2; tr++)
#pragma unroll
            for (int tc = 0; tc < 4; tc++)
                acc[tr][tc] = __builtin_amdgcn_mfma_f32_16x16x32_bf16(a[tr], b[tc],
                                                                      acc[tr][tc], 0, 0, 0);
    }

    // epilogue: C/D layout col=lane&15, row=(lane>>4)*4+r
#pragma unroll
    for (int tc = 0; tc < 4; tc++) {
        int c = cw + tc * 16 + lm;
        float psc, psh;
        if (MODE == 1) {
            float sc = g[c] * rsqrtf(vr[c] + EPS_BN);
            psc = sc;
            psh = be[c] + (bias[c] - mn[c]) * sc;
        } else if (MODE == 2) {
            psc = 1.0f;
            psh = bias[c];
        } else {
            psc = 1.0f;
            psh = 0.0f;
        }
#pragma unroll
        for (int tr = 0; tr < 2; tr++) {
#pragma unroll
            for (int r = 0; r < 4; r++) {
                int row = row0 + rw + tr * 16 + lq * 4 + r;
                if (row < nrows) {
                    float v = acc[tr][tc][r] * psc + psh;
                    if (MODE != 0) v = fmaxf(v, 0.0f);
                    if (MODE == 2)
                        ((float*)Y)[(size_t)row * 128 + c] = v;
                    else
                        ((ushort*)Y)[(size_t)row * 128 + c] = f2bf(v);
                }
            }
        }
    }
}

// ---------------- head: softplus(h1 @ Wo + bo) ----------------
__global__ __launch_bounds__(256) void head_k(const float* __restrict__ h1,
                                              const float* __restrict__ Wo,
                                              const float* __restrict__ bo,
                                              float* __restrict__ out, int n) {
    int gtid = blockIdx.x * 256 + threadIdx.x;
    int node = gtid >> 6;
    if (node >= n) return;
    int lane = threadIdx.x & 63;
    float2 hv = *(const float2*)&h1[(size_t)node * 128 + lane * 2];
    float2 wv = *(const float2*)&Wo[lane * 2];
    float p = hv.x * wv.x + hv.y * wv.y;
#pragma unroll
    for (int off = 32; off > 0; off >>= 1) p += __shfl_down(p, off, 64);
    if (lane == 0) {
        float x = p + bo[0];
        out[node] = fmaxf(x, 0.0f) + log1pf(expf(-fabsf(x)));
    }
}

extern "C" void kernel_launch(void* const* d_in, const int* in_sizes, int n_in,
                              void* d_out, int out_size, void* d_ws, size_t ws_size,
                              hipStream_t stream) {
    const float* x = (const float*)d_in[0];
    const int* ei = (const int*)d_in[1];
    const int N = in_sizes[0] / 128;
    const int E = in_sizes[1] / 2;
    const int* srcv = ei;
    const int* dstv = ei + E;
    const float* W1 = (const float*)d_in[2];  const float* b1 = (const float*)d_in[3];
    const float* W2 = (const float*)d_in[4];  const float* b2 = (const float*)d_in[5];
    const float* Wf1 = (const float*)d_in[6]; const float* bf1 = (const float*)d_in[7];
    const float* Wf2 = (const float*)d_in[8]; const float* bf2 = (const float*)d_in[9];
    const float* Wo = (const float*)d_in[10]; const float* bo = (const float*)d_in[11];
    const float* g1 = (const float*)d_in[12], *be1 = (const float*)d_in[13],
               *m1 = (const float*)d_in[14], *v1 = (const float*)d_in[15];
    const float* g2 = (const float*)d_in[16], *be2 = (const float*)d_in[17],
               *m2 = (const float*)d_in[18], *v2 = (const float*)d_in[19];
    const float* g3 = (const float*)d_in[20], *be3 = (const float*)d_in[21],
               *m3 = (const float*)d_in[22], *v3 = (const float*)d_in[23];

    // ---- workspace carve-up ----
    char* ws = (char*)d_ws;
    size_t off = 0;
    auto carve = [&](size_t bytes) {
        char* p = ws + off;
        off = (off + bytes + 255) & ~(size_t)255;
        return p;
    };
    int nb = (N + 255) / 256;
    int* cnt = (int*)carve((size_t)N * 4);
    int* bsum = (int*)carve((size_t)((nb + 1023) & ~1023) * 4);
    int* rowstart = (int*)carve((size_t)(N + 1) * 4);
    int* cursor = (int*)carve((size_t)N * 4);
    int* col = (int*)carve((size_t)E * 4);
    float* dinv = (float*)carve((size_t)N * 4);
    ushort* XB = (ushort*)carve((size_t)N * 128 * 2);
    ushort* bufA = (ushort*)carve((size_t)N * 128 * 2);
    ushort* bufB = (ushort*)carve((size_t)N * 128 * 2);
    ushort* Wt1 = (ushort*)carve(128 * 128 * 2);
    ushort* Wt2 = (ushort*)carve(128 * 128 * 2);
    ushort* Wtf1 = (ushort*)carve(128 * 128 * 2);
    ushort* Wtf2 = (ushort*)carve(128 * 128 * 2);

    float* out_pred = (float*)d_out;
    float* out_h1 = out_pred + N;

    const int gblocks = (N + 63) / 64;
    const int eblocks = (E + 255) / 256;
    const int nblocks = nb;
    const int wblocks = (N + 3) / 4;
    const int hblocks = (int)(((size_t)N * 64 + 255) / 256);
    const int cblocks = (int)(((size_t)N * 128 / 4 + 255) / 256);

    // ---- CSR build ----
    hipMemsetAsync(cnt, 0, (size_t)N * 4, stream);
    hist_k<<<eblocks, 256, 0, stream>>>(dstv, cnt, E);
    scan1_k<<<nblocks, 256, 0, stream>>>(cnt, bsum, N);
    scan2_k<<<1, 1024, 0, stream>>>(bsum, nblocks);
    scan3_k<<<nblocks, 256, 0, stream>>>(cnt, bsum, rowstart, cursor, N, E);
    fill_k<<<eblocks, 256, 0, stream>>>(srcv, dstv, cursor, col, E);
    dinv_k<<<nblocks, 256, 0, stream>>>(cnt, dinv, N);

    // ---- dtype prep ----
    cvt_bf16_k<<<cblocks, 256, 0, stream>>>(x, XB, N * 128 / 4);
    prep_wt_k<<<64, 256, 0, stream>>>(W1, Wt1);
    prep_wt_k<<<64, 256, 0, stream>>>(W2, Wt2);
    prep_wt_k<<<64, 256, 0, stream>>>(Wf1, Wtf1);
    prep_wt_k<<<64, 256, 0, stream>>>(Wf2, Wtf2);

    // layer 1: h = relu(bn1(conv(x@W1) + b1))
    mfma_gemm_k<0><<<gblocks, 256, 0, stream>>>(XB, Wt1, nullptr, nullptr, nullptr,
                                                nullptr, nullptr, bufA, N);
    gather_k<<<wblocks, 256, 0, stream>>>(bufA, rowstart, col, dinv, b1, g1, be1, m1, v1,
                                          bufB, N);

    // layer 2: h = relu(bn2(conv(h@W2) + b2))
    mfma_gemm_k<0><<<gblocks, 256, 0, stream>>>(bufB, Wt2, nullptr, nullptr, nullptr,
                                                nullptr, nullptr, bufA, N);
    gather_k<<<wblocks, 256, 0, stream>>>(bufA, rowstart, col, dinv, b2, g2, be2, m2, v2,
                                          bufB, N);

    // layer 3: h = relu(bn3(h@Wf1 + bf1))
    mfma_gemm_k<1><<<gblocks, 256, 0, stream>>>(bufB, Wtf1, bf1, g3, be3, m3, v3, bufA, N);

    // layer 4: h1 = relu(h@Wf2 + bf2) -> f32 straight into d_out
    mfma_gemm_k<2><<<gblocks, 256, 0, stream>>>(bufA, Wtf2, bf2, nullptr, nullptr, nullptr,
                                                nullptr, out_h1, N);

    // head: raw_pred = softplus(h1@Wo + bo)
    head_k<<<hblocks, 256, 0, stream>>>(out_h1, Wo, bo, out_pred, N);
}

// Round 4
// 452.039 us; speedup vs baseline: 6.8362x; 1.4179x over previous
//
#include <hip/hip_runtime.h>
#include <math.h>

#define EPS_BN 1e-5f
#define MAXNB 512  // max coarse buckets (N <= 131072)

typedef __attribute__((ext_vector_type(8))) short bf16x8;
typedef __attribute__((ext_vector_type(4))) float f32x4;

__device__ __forceinline__ ushort f2bf(float f) {
    uint u = __float_as_uint(f);
    u += 0x7FFF + ((u >> 16) & 1);  // RTN-even
    return (ushort)(u >> 16);
}
__device__ __forceinline__ float bf2f(uint h) {
    return __uint_as_float(h << 16);
}

// ================= bucketed CSR build =================
// coarse histogram of dst>>8, LDS-privatized
__global__ __launch_bounds__(256) void chist_k(const int* __restrict__ dst,
                                               int* __restrict__ bcnt, int nE, int NB) {
    __shared__ int s[MAXNB];
    for (int i = threadIdx.x; i < NB; i += 256) s[i] = 0;
    __syncthreads();
    int base = blockIdx.x * 4096;
#pragma unroll
    for (int i = 0; i < 16; i++) {
        int e = base + i * 256 + threadIdx.x;
        if (e < nE) atomicAdd(&s[dst[e] >> 8], 1);
    }
    __syncthreads();
    for (int i = threadIdx.x; i < NB; i += 256)
        if (s[i]) atomicAdd(&bcnt[i], s[i]);
}

// exclusive scan of bucket counts (single block)
__global__ __launch_bounds__(512) void cscan_k(const int* __restrict__ bcnt,
                                               int* __restrict__ bstart,
                                               int* __restrict__ bcur,
                                               int* __restrict__ rowstart,
                                               int NB, int nE, int N) {
    __shared__ int s[512];
    int t = threadIdx.x;
    int c = (t < NB) ? bcnt[t] : 0;
    s[t] = c;
    __syncthreads();
    for (int off = 1; off < 512; off <<= 1) {
        int v = (t >= off) ? s[t - off] : 0;
        __syncthreads();
        s[t] += v;
        __syncthreads();
    }
    int ex = s[t] - c;
    if (t < NB) {
        bstart[t] = ex;
        bcur[t] = ex;
    }
    if (t == 0) {
        bstart[NB] = nE;
        rowstart[N] = nE;
    }
}

// phase A: tile-ranked scatter of (src,dst) into coarse-bucket-grouped array
__global__ __launch_bounds__(256) void bucketA_k(const int* __restrict__ src,
                                                 const int* __restrict__ dst,
                                                 int* __restrict__ bcur,
                                                 int2* __restrict__ coarse, int nE, int NB) {
    __shared__ int cnt[MAXNB];
    __shared__ int basix[MAXNB];
    const int tid = threadIdx.x;
    for (int i = tid; i < NB; i += 256) cnt[i] = 0;
    __syncthreads();
    int base = blockIdx.x * 4096;
    int es[16], ed[16], rk[16];
#pragma unroll
    for (int i = 0; i < 16; i++) {
        int e = base + i * 256 + tid;
        if (e < nE) {
            es[i] = src[e];
            ed[i] = dst[e];
            rk[i] = atomicAdd(&cnt[ed[i] >> 8], 1);
        } else {
            ed[i] = -1;
        }
    }
    __syncthreads();
    for (int i = tid; i < NB; i += 256)
        if (cnt[i]) basix[i] = atomicAdd(&bcur[i], cnt[i]);
    __syncthreads();
#pragma unroll
    for (int i = 0; i < 16; i++) {
        if (ed[i] >= 0) {
            int2 pr = {es[i], ed[i]};
            coarse[basix[ed[i] >> 8] + rk[i]] = pr;
        }
    }
}

// phase B: per-bucket exact CSR (rowstart, col, dinv); writes stay in one L2 window
__global__ __launch_bounds__(256) void bucketB_k(const int2* __restrict__ coarse,
                                                 const int* __restrict__ bstart,
                                                 int* __restrict__ rowstart,
                                                 int* __restrict__ col,
                                                 float* __restrict__ dinv, int N) {
    __shared__ int cnt[256];
    __shared__ int s[256];
    __shared__ int cur[256];
    const int tid = threadIdx.x;
    const int b = blockIdx.x;
    const int beg = bstart[b], end = bstart[b + 1];
    cnt[tid] = 0;
    __syncthreads();
    for (int p = beg + tid; p < end; p += 256) atomicAdd(&cnt[coarse[p].y & 255], 1);
    __syncthreads();
    int c = cnt[tid];
    s[tid] = c;
    __syncthreads();
    for (int off = 1; off < 256; off <<= 1) {
        int v = (tid >= off) ? s[tid - off] : 0;
        __syncthreads();
        s[tid] += v;
        __syncthreads();
    }
    int ex = s[tid] - c;
    int node = b * 256 + tid;
    if (node < N) {
        rowstart[node] = beg + ex;
        dinv[node] = rsqrtf((float)c + 1.0f);  // +1 = self loop
    }
    cur[tid] = ex;
    __syncthreads();
    for (int p = beg + tid; p < end; p += 256) {
        int2 e = coarse[p];
        int r = atomicAdd(&cur[e.y & 255], 1);
        col[beg + r] = e.x;
    }
}

// ================= dtype prep =================
__global__ __launch_bounds__(256) void cvt_bf16_k(const float* __restrict__ x,
                                                  ushort* __restrict__ xb, int n4) {
    int i = blockIdx.x * 256 + threadIdx.x;
    if (i >= n4) return;
    float4 v = *(const float4*)&x[(size_t)i * 4];
    ushort4 o = {f2bf(v.x), f2bf(v.y), f2bf(v.z), f2bf(v.w)};
    *(ushort4*)&xb[(size_t)i * 4] = o;
}

__global__ __launch_bounds__(256) void prep_wt_k(const float* __restrict__ W,
                                                 ushort* __restrict__ Wt) {
    int i = blockIdx.x * 256 + threadIdx.x;  // < 16384
    int n = i >> 7, k = i & 127;
    Wt[n * 128 + k] = f2bf(W[k * 128 + n]);
}

// ============ gather conv (bf16 in/out): relu(bn(sum + selfloop + bias)) ============
__global__ __launch_bounds__(256) void gather_k(const ushort* __restrict__ h,
                                                const int* __restrict__ rowstart,
                                                const int* __restrict__ col,
                                                const float* __restrict__ dinv,
                                                const float* __restrict__ bias,
                                                const float* __restrict__ g,
                                                const float* __restrict__ be,
                                                const float* __restrict__ mn,
                                                const float* __restrict__ vr,
                                                ushort* __restrict__ out, int n) {
    int node = blockIdx.x * 4 + (threadIdx.x >> 6);
    if (node >= n) return;
    int lane = threadIdx.x & 63;
    int c = lane * 2;
    int beg = rowstart[node], end = rowstart[node + 1];
    float dd = dinv[node];
    uint hp = *(const uint*)&h[(size_t)node * 128 + c];
    float acc0 = bf2f(hp & 0xffffu) * dd * dd;  // self loop
    float acc1 = bf2f(hp >> 16) * dd * dd;
    int p = beg;
    for (; p + 3 < end; p += 4) {
        int s0 = col[p], s1 = col[p + 1], s2 = col[p + 2], s3 = col[p + 3];
        float n0 = dinv[s0] * dd, n1 = dinv[s1] * dd;
        float n2 = dinv[s2] * dd, n3 = dinv[s3] * dd;
        uint a = *(const uint*)&h[(size_t)s0 * 128 + c];
        uint b = *(const uint*)&h[(size_t)s1 * 128 + c];
        uint d2 = *(const uint*)&h[(size_t)s2 * 128 + c];
        uint d3 = *(const uint*)&h[(size_t)s3 * 128 + c];
        acc0 = fmaf(bf2f(a & 0xffffu), n0, acc0);
        acc1 = fmaf(bf2f(a >> 16), n0, acc1);
        acc0 = fmaf(bf2f(b & 0xffffu), n1, acc0);
        acc1 = fmaf(bf2f(b >> 16), n1, acc1);
        acc0 = fmaf(bf2f(d2 & 0xffffu), n2, acc0);
        acc1 = fmaf(bf2f(d2 >> 16), n2, acc1);
        acc0 = fmaf(bf2f(d3 & 0xffffu), n3, acc0);
        acc1 = fmaf(bf2f(d3 >> 16), n3, acc1);
    }
    for (; p < end; p++) {
        int s0 = col[p];
        float n0 = dinv[s0] * dd;
        uint a = *(const uint*)&h[(size_t)s0 * 128 + c];
        acc0 = fmaf(bf2f(a & 0xffffu), n0, acc0);
        acc1 = fmaf(bf2f(a >> 16), n0, acc1);
    }
    float sc0 = g[c] * rsqrtf(vr[c] + EPS_BN);
    float sc1 = g[c + 1] * rsqrtf(vr[c + 1] + EPS_BN);
    float o0 = fmaxf((acc0 + bias[c] - mn[c]) * sc0 + be[c], 0.0f);
    float o1 = fmaxf((acc1 + bias[c + 1] - mn[c + 1]) * sc1 + be[c + 1], 0.0f);
    uint r = (uint)f2bf(o0) | ((uint)f2bf(o1) << 16);
    *(uint*)&out[(size_t)node * 128 + c] = r;
}

// ============ MFMA GEMM: Y = X(n,128) @ W(128,128), fused epilogues ============
// MODE 0: raw -> bf16   MODE 1: relu(bn(v+bias)) -> bf16   MODE 2: relu(v+bias) -> f32
template <int MODE>
__global__ __launch_bounds__(256) void mfma_gemm_k(const ushort* __restrict__ Xb,
                                                   const ushort* __restrict__ Wt,
                                                   const float* __restrict__ bias,
                                                   const float* __restrict__ g,
                                                   const float* __restrict__ be,
                                                   const float* __restrict__ mn,
                                                   const float* __restrict__ vr,
                                                   void* __restrict__ Y, int nrows) {
    constexpr int LDK = 136;           // 128 + 8 pad
    __shared__ ushort sX[64 * LDK];
    __shared__ ushort sW[128 * LDK];
    const int tid = threadIdx.x;
    const int row0 = blockIdx.x * 64;

#pragma unroll
    for (int i = 0; i < 8; i++) {
        int c = tid + i * 256;
        int r = c >> 4, o = c & 15;
        *(int4*)&sW[r * LDK + o * 8] = *(const int4*)&Wt[r * 128 + o * 8];
    }
#pragma unroll
    for (int i = 0; i < 4; i++) {
        int c = tid + i * 256;
        int r = c >> 4, o = c & 15;
        int rg = row0 + r;
        if (rg >= nrows) rg = nrows - 1;
        *(int4*)&sX[r * LDK + o * 8] = *(const int4*)&Xb[(size_t)rg * 128 + o * 8];
    }
    __syncthreads();

    const int wave = tid >> 6, lane = tid & 63;
    const int rw = (wave >> 1) * 32;
    const int cw = (wave & 1) * 64;
    const int lm = lane & 15, lq = lane >> 4;

    f32x4 acc[2][4];
#pragma unroll
    for (int tr = 0; tr < 2; tr++)
#pragma unroll
        for (int tc = 0; tc < 4; tc++) acc[tr][tc] = (f32x4){0.f, 0.f, 0.f, 0.f};

#pragma unroll
    for (int ks = 0; ks < 4; ks++) {
        int kb = ks * 32 + lq * 8;
        bf16x8 a[2], b[4];
#pragma unroll
        for (int tr = 0; tr < 2; tr++)
            a[tr] = *(bf16x8*)&sX[(rw + tr * 16 + lm) * LDK + kb];
#pragma unroll
        for (int tc = 0; tc < 4; tc++)
            b[tc] = *(bf16x8*)&sW[(cw + tc * 16 + lm) * LDK + kb];
#pragma unroll
        for (int tr = 0; tr < 2; tr++)
#pragma unroll
            for (int tc = 0; tc < 4; tc++)
                acc[tr][tc] = __builtin_amdgcn_mfma_f32_16x16x32_bf16(a[tr], b[tc],
                                                                      acc[tr][tc], 0, 0, 0);
    }

#pragma unroll
    for (int tc = 0; tc < 4; tc++) {
        int c = cw + tc * 16 + lm;
        float psc, psh;
        if (MODE == 1) {
            float sc = g[c] * rsqrtf(vr[c] + EPS_BN);
            psc = sc;
            psh = be[c] + (bias[c] - mn[c]) * sc;
        } else if (MODE == 2) {
            psc = 1.0f;
            psh = bias[c];
        } else {
            psc = 1.0f;
            psh = 0.0f;
        }
#pragma unroll
        for (int tr = 0; tr < 2; tr++) {
#pragma unroll
            for (int r = 0; r < 4; r++) {
                int row = row0 + rw + tr * 16 + lq * 4 + r;
                if (row < nrows) {
                    float v = acc[tr][tc][r] * psc + psh;
                    if (MODE != 0) v = fmaxf(v, 0.0f);
                    if (MODE == 2)
                        ((float*)Y)[(size_t)row * 128 + c] = v;
                    else
                        ((ushort*)Y)[(size_t)row * 128 + c] = f2bf(v);
                }
            }
        }
    }
}

// ---------------- head: softplus(h1 @ Wo + bo) ----------------
__global__ __launch_bounds__(256) void head_k(const float* __restrict__ h1,
                                              const float* __restrict__ Wo,
                                              const float* __restrict__ bo,
                                              float* __restrict__ out, int n) {
    int gtid = blockIdx.x * 256 + threadIdx.x;
    int node = gtid >> 6;
    if (node >= n) return;
    int lane = threadIdx.x & 63;
    float2 hv = *(const float2*)&h1[(size_t)node * 128 + lane * 2];
    float2 wv = *(const float2*)&Wo[lane * 2];
    float p = hv.x * wv.x + hv.y * wv.y;
#pragma unroll
    for (int off = 32; off > 0; off >>= 1) p += __shfl_down(p, off, 64);
    if (lane == 0) {
        float x = p + bo[0];
        out[node] = fmaxf(x, 0.0f) + log1pf(expf(-fabsf(x)));
    }
}

extern "C" void kernel_launch(void* const* d_in, const int* in_sizes, int n_in,
                              void* d_out, int out_size, void* d_ws, size_t ws_size,
                              hipStream_t stream) {
    const float* x = (const float*)d_in[0];
    const int* ei = (const int*)d_in[1];
    const int N = in_sizes[0] / 128;
    const int E = in_sizes[1] / 2;
    const int* srcv = ei;
    const int* dstv = ei + E;
    const float* W1 = (const float*)d_in[2];  const float* b1 = (const float*)d_in[3];
    const float* W2 = (const float*)d_in[4];  const float* b2 = (const float*)d_in[5];
    const float* Wf1 = (const float*)d_in[6]; const float* bf1 = (const float*)d_in[7];
    const float* Wf2 = (const float*)d_in[8]; const float* bf2 = (const float*)d_in[9];
    const float* Wo = (const float*)d_in[10]; const float* bo = (const float*)d_in[11];
    const float* g1 = (const float*)d_in[12], *be1 = (const float*)d_in[13],
               *m1 = (const float*)d_in[14], *v1 = (const float*)d_in[15];
    const float* g2 = (const float*)d_in[16], *be2 = (const float*)d_in[17],
               *m2 = (const float*)d_in[18], *v2 = (const float*)d_in[19];
    const float* g3 = (const float*)d_in[20], *be3 = (const float*)d_in[21],
               *m3 = (const float*)d_in[22], *v3 = (const float*)d_in[23];

    // ---- workspace carve-up ----
    char* ws = (char*)d_ws;
    size_t off = 0;
    auto carve = [&](size_t bytes) {
        char* p = ws + off;
        off = (off + bytes + 255) & ~(size_t)255;
        return p;
    };
    const int NB = (N + 255) >> 8;  // coarse buckets of 256 nodes
    int* bcnt = (int*)carve((size_t)MAXNB * 4);
    int* bstart = (int*)carve((size_t)(MAXNB + 1) * 4);
    int* bcur = (int*)carve((size_t)MAXNB * 4);
    int* rowstart = (int*)carve((size_t)(N + 1) * 4);
    int* col = (int*)carve((size_t)E * 4);
    int2* coarse = (int2*)carve((size_t)E * 8);
    float* dinv = (float*)carve((size_t)N * 4);
    ushort* XB = (ushort*)carve((size_t)N * 128 * 2);
    ushort* bufA = (ushort*)carve((size_t)N * 128 * 2);
    ushort* bufB = (ushort*)carve((size_t)N * 128 * 2);
    ushort* Wt1 = (ushort*)carve(128 * 128 * 2);
    ushort* Wt2 = (ushort*)carve(128 * 128 * 2);
    ushort* Wtf1 = (ushort*)carve(128 * 128 * 2);
    ushort* Wtf2 = (ushort*)carve(128 * 128 * 2);

    float* out_pred = (float*)d_out;
    float* out_h1 = out_pred + N;

    const int gblocks = (N + 63) / 64;
    const int tblocks = (E + 4095) / 4096;
    const int wblocks = (N + 3) / 4;
    const int hblocks = (int)(((size_t)N * 64 + 255) / 256);
    const int cblocks = (int)(((size_t)N * 128 / 4 + 255) / 256);

    // ---- bucketed CSR build ----
    hipMemsetAsync(bcnt, 0, (size_t)MAXNB * 4, stream);
    chist_k<<<tblocks, 256, 0, stream>>>(dstv, bcnt, E, NB);
    cscan_k<<<1, 512, 0, stream>>>(bcnt, bstart, bcur, rowstart, NB, E, N);
    bucketA_k<<<tblocks, 256, 0, stream>>>(srcv, dstv, bcur, coarse, E, NB);
    bucketB_k<<<NB, 256, 0, stream>>>(coarse, bstart, rowstart, col, dinv, N);

    // ---- dtype prep ----
    cvt_bf16_k<<<cblocks, 256, 0, stream>>>(x, XB, N * 128 / 4);
    prep_wt_k<<<64, 256, 0, stream>>>(W1, Wt1);
    prep_wt_k<<<64, 256, 0, stream>>>(W2, Wt2);
    prep_wt_k<<<64, 256, 0, stream>>>(Wf1, Wtf1);
    prep_wt_k<<<64, 256, 0, stream>>>(Wf2, Wtf2);

    // layer 1: h = relu(bn1(conv(x@W1) + b1))
    mfma_gemm_k<0><<<gblocks, 256, 0, stream>>>(XB, Wt1, nullptr, nullptr, nullptr,
                                                nullptr, nullptr, bufA, N);
    gather_k<<<wblocks, 256, 0, stream>>>(bufA, rowstart, col, dinv, b1, g1, be1, m1, v1,
                                          bufB, N);

    // layer 2: h = relu(bn2(conv(h@W2) + b2))
    mfma_gemm_k<0><<<gblocks, 256, 0, stream>>>(bufB, Wt2, nullptr, nullptr, nullptr,
                                                nullptr, nullptr, bufA, N);
    gather_k<<<wblocks, 256, 0, stream>>>(bufA, rowstart, col, dinv, b2, g2, be2, m2, v2,
                                          bufB, N);

    // layer 3: h = relu(bn3(h@Wf1 + bf1))
    mfma_gemm_k<1><<<gblocks, 256, 0, stream>>>(bufB, Wtf1, bf1, g3, be3, m3, v3, bufA, N);

    // layer 4: h1 = relu(h@Wf2 + bf2) -> f32 straight into d_out
    mfma_gemm_k<2><<<gblocks, 256, 0, stream>>>(bufA, Wtf2, bf2, nullptr, nullptr, nullptr,
                                                nullptr, out_h1, N);

    // head: raw_pred = softplus(h1@Wo + bo)
    head_k<<<hblocks, 256, 0, stream>>>(out_h1, Wo, bo, out_pred, N);
}

// Round 5
// 441.351 us; speedup vs baseline: 7.0018x; 1.0242x over previous
//
#include <hip/hip_runtime.h>
#include <math.h>

#define EPS_BN 1e-5f
#define MAXNB 512  // max coarse buckets (N <= 131072); also assumes N < 2^24

typedef __attribute__((ext_vector_type(8))) short bf16x8;
typedef __attribute__((ext_vector_type(4))) float f32x4;

__device__ __forceinline__ ushort f2bf(float f) {
    uint u = __float_as_uint(f);
    u += 0x7FFF + ((u >> 16) & 1);  // RTN-even
    return (ushort)(u >> 16);
}
__device__ __forceinline__ float bf2f(uint h) {
    return __uint_as_float(h << 16);
}

// ================= bucketed CSR build =================
__global__ __launch_bounds__(256) void chist_k(const int* __restrict__ dst,
                                               int* __restrict__ bcnt, int nE, int NB) {
    __shared__ int s[MAXNB];
    for (int i = threadIdx.x; i < NB; i += 256) s[i] = 0;
    __syncthreads();
    int base = blockIdx.x * 4096;
#pragma unroll
    for (int i = 0; i < 16; i++) {
        int e = base + i * 256 + threadIdx.x;
        if (e < nE) atomicAdd(&s[dst[e] >> 8], 1);
    }
    __syncthreads();
    for (int i = threadIdx.x; i < NB; i += 256)
        if (s[i]) atomicAdd(&bcnt[i], s[i]);
}

__global__ __launch_bounds__(512) void cscan_k(const int* __restrict__ bcnt,
                                               int* __restrict__ bstart,
                                               int* __restrict__ bcur,
                                               int* __restrict__ rowstart,
                                               int NB, int nE, int N) {
    __shared__ int s[512];
    int t = threadIdx.x;
    int c = (t < NB) ? bcnt[t] : 0;
    s[t] = c;
    __syncthreads();
    for (int off = 1; off < 512; off <<= 1) {
        int v = (t >= off) ? s[t - off] : 0;
        __syncthreads();
        s[t] += v;
        __syncthreads();
    }
    int ex = s[t] - c;
    if (t < NB) {
        bstart[t] = ex;
        bcur[t] = ex;
    }
    if (t == 0) {
        bstart[NB] = nE;
        rowstart[N] = nE;
    }
}

// phase A: tile-ranked scatter; coarse entry packed: src | (dst&255)<<24
__global__ __launch_bounds__(256) void bucketA_k(const int* __restrict__ src,
                                                 const int* __restrict__ dst,
                                                 int* __restrict__ bcur,
                                                 int* __restrict__ coarse, int nE, int NB) {
    __shared__ int cnt[MAXNB];
    __shared__ int basix[MAXNB];
    const int tid = threadIdx.x;
    for (int i = tid; i < NB; i += 256) cnt[i] = 0;
    __syncthreads();
    int base = blockIdx.x * 4096;
    int es[16], ed[16], rk[16];
#pragma unroll
    for (int i = 0; i < 16; i++) {
        int e = base + i * 256 + tid;
        if (e < nE) {
            es[i] = src[e];
            ed[i] = dst[e];
            rk[i] = atomicAdd(&cnt[ed[i] >> 8], 1);
        } else {
            ed[i] = -1;
        }
    }
    __syncthreads();
    for (int i = tid; i < NB; i += 256)
        if (cnt[i]) basix[i] = atomicAdd(&bcur[i], cnt[i]);
    __syncthreads();
#pragma unroll
    for (int i = 0; i < 16; i++) {
        if (ed[i] >= 0)
            coarse[basix[ed[i] >> 8] + rk[i]] = es[i] | ((ed[i] & 255) << 24);
    }
}

// phase B: per-bucket exact CSR
__global__ __launch_bounds__(256) void bucketB_k(const int* __restrict__ coarse,
                                                 const int* __restrict__ bstart,
                                                 int* __restrict__ rowstart,
                                                 int* __restrict__ col,
                                                 float* __restrict__ dinv, int N) {
    __shared__ int cnt[256];
    __shared__ int s[256];
    __shared__ int cur[256];
    const int tid = threadIdx.x;
    const int b = blockIdx.x;
    const int beg = bstart[b], end = bstart[b + 1];
    cnt[tid] = 0;
    __syncthreads();
    for (int p = beg + tid; p < end; p += 256)
        atomicAdd(&cnt[((uint)coarse[p]) >> 24], 1);
    __syncthreads();
    int c = cnt[tid];
    s[tid] = c;
    __syncthreads();
    for (int off = 1; off < 256; off <<= 1) {
        int v = (tid >= off) ? s[tid - off] : 0;
        __syncthreads();
        s[tid] += v;
        __syncthreads();
    }
    int ex = s[tid] - c;
    int node = b * 256 + tid;
    if (node < N) {
        rowstart[node] = beg + ex;
        dinv[node] = rsqrtf((float)c + 1.0f);  // +1 = self loop
    }
    cur[tid] = ex;
    __syncthreads();
    for (int p = beg + tid; p < end; p += 256) {
        int v = coarse[p];
        int r = atomicAdd(&cur[((uint)v) >> 24], 1);
        col[beg + r] = v & 0xFFFFFF;
    }
}

// ================= dtype prep =================
__global__ __launch_bounds__(256) void cvt_bf16_k(const float* __restrict__ x,
                                                  ushort* __restrict__ xb, int n4) {
    int i = blockIdx.x * 256 + threadIdx.x;
    if (i >= n4) return;
    float4 v = *(const float4*)&x[(size_t)i * 4];
    ushort4 o = {f2bf(v.x), f2bf(v.y), f2bf(v.z), f2bf(v.w)};
    *(ushort4*)&xb[(size_t)i * 4] = o;
}

// all 4 weight transposes in one launch: 256 blocks, which = blockIdx.x>>6
__global__ __launch_bounds__(256) void prep_wt_all_k(const float* __restrict__ W1,
                                                     const float* __restrict__ W2,
                                                     const float* __restrict__ W3,
                                                     const float* __restrict__ W4,
                                                     ushort* __restrict__ T1,
                                                     ushort* __restrict__ T2,
                                                     ushort* __restrict__ T3,
                                                     ushort* __restrict__ T4) {
    int which = blockIdx.x >> 6;
    const float* W = (which == 0) ? W1 : (which == 1) ? W2 : (which == 2) ? W3 : W4;
    ushort* T = (which == 0) ? T1 : (which == 1) ? T2 : (which == 2) ? T3 : T4;
    int i = (blockIdx.x & 63) * 256 + threadIdx.x;  // < 16384
    int n = i >> 7, k = i & 127;
    T[n * 128 + k] = f2bf(W[k * 128 + n]);
}

// ============ gather conv (bf16 in/out): relu(bn(sum + selfloop + bias)) ============
// one wave per node; 16 lanes per edge-row (8 ch/lane, uint4 = 16B), 4 edges/wave-step
__global__ __launch_bounds__(256) void gather_k(const ushort* __restrict__ h,
                                                const int* __restrict__ rowstart,
                                                const int* __restrict__ col,
                                                const float* __restrict__ dinv,
                                                const float* __restrict__ bias,
                                                const float* __restrict__ g,
                                                const float* __restrict__ be,
                                                const float* __restrict__ mn,
                                                const float* __restrict__ vr,
                                                ushort* __restrict__ out, int n) {
    int node = blockIdx.x * 4 + (threadIdx.x >> 6);
    if (node >= n) return;
    int lane = threadIdx.x & 63;
    int grp = lane >> 4;   // 0..3: which edge in the 4-edge step
    int li = lane & 15;    // channel group: 8 ch
    int c = li * 8;
    int beg = rowstart[node], end = rowstart[node + 1];
    float dd = dinv[node];
    float acc[8] = {0.f, 0.f, 0.f, 0.f, 0.f, 0.f, 0.f, 0.f};

    if (grp == 0) {  // self loop
        uint4 rv = *(const uint4*)&h[(size_t)node * 128 + c];
        float sl = dd * dd;
        acc[0] = bf2f(rv.x & 0xffffu) * sl; acc[1] = bf2f(rv.x >> 16) * sl;
        acc[2] = bf2f(rv.y & 0xffffu) * sl; acc[3] = bf2f(rv.y >> 16) * sl;
        acc[4] = bf2f(rv.z & 0xffffu) * sl; acc[5] = bf2f(rv.z >> 16) * sl;
        acc[6] = bf2f(rv.w & 0xffffu) * sl; acc[7] = bf2f(rv.w >> 16) * sl;
    }

    int p = beg + grp;
    for (; p + 4 < end; p += 8) {  // 2 edges per group per iter = 8 edges/wave
        int s0 = col[p], s1 = col[p + 4];
        float n0 = dinv[s0] * dd, n1 = dinv[s1] * dd;
        uint4 a = *(const uint4*)&h[(size_t)s0 * 128 + c];
        uint4 b = *(const uint4*)&h[(size_t)s1 * 128 + c];
        acc[0] = fmaf(bf2f(a.x & 0xffffu), n0, acc[0]);
        acc[1] = fmaf(bf2f(a.x >> 16), n0, acc[1]);
        acc[2] = fmaf(bf2f(a.y & 0xffffu), n0, acc[2]);
        acc[3] = fmaf(bf2f(a.y >> 16), n0, acc[3]);
        acc[4] = fmaf(bf2f(a.z & 0xffffu), n0, acc[4]);
        acc[5] = fmaf(bf2f(a.z >> 16), n0, acc[5]);
        acc[6] = fmaf(bf2f(a.w & 0xffffu), n0, acc[6]);
        acc[7] = fmaf(bf2f(a.w >> 16), n0, acc[7]);
        acc[0] = fmaf(bf2f(b.x & 0xffffu), n1, acc[0]);
        acc[1] = fmaf(bf2f(b.x >> 16), n1, acc[1]);
        acc[2] = fmaf(bf2f(b.y & 0xffffu), n1, acc[2]);
        acc[3] = fmaf(bf2f(b.y >> 16), n1, acc[3]);
        acc[4] = fmaf(bf2f(b.z & 0xffffu), n1, acc[4]);
        acc[5] = fmaf(bf2f(b.z >> 16), n1, acc[5]);
        acc[6] = fmaf(bf2f(b.w & 0xffffu), n1, acc[6]);
        acc[7] = fmaf(bf2f(b.w >> 16), n1, acc[7]);
    }
    if (p < end) {
        int s0 = col[p];
        float n0 = dinv[s0] * dd;
        uint4 a = *(const uint4*)&h[(size_t)s0 * 128 + c];
        acc[0] = fmaf(bf2f(a.x & 0xffffu), n0, acc[0]);
        acc[1] = fmaf(bf2f(a.x >> 16), n0, acc[1]);
        acc[2] = fmaf(bf2f(a.y & 0xffffu), n0, acc[2]);
        acc[3] = fmaf(bf2f(a.y >> 16), n0, acc[3]);
        acc[4] = fmaf(bf2f(a.z & 0xffffu), n0, acc[4]);
        acc[5] = fmaf(bf2f(a.z >> 16), n0, acc[5]);
        acc[6] = fmaf(bf2f(a.w & 0xffffu), n0, acc[6]);
        acc[7] = fmaf(bf2f(a.w >> 16), n0, acc[7]);
    }
    // reduce the 4 lane-groups (lanes l, l+16, l+32, l+48 hold same channels)
#pragma unroll
    for (int j = 0; j < 8; j++) {
        acc[j] += __shfl_xor(acc[j], 16, 64);
        acc[j] += __shfl_xor(acc[j], 32, 64);
    }
    if (grp == 0) {
        uint r[4];
#pragma unroll
        for (int j = 0; j < 4; j++) {
            int cc = c + j * 2;
            float sc0 = g[cc] * rsqrtf(vr[cc] + EPS_BN);
            float sc1 = g[cc + 1] * rsqrtf(vr[cc + 1] + EPS_BN);
            float o0 = fmaxf((acc[j * 2] + bias[cc] - mn[cc]) * sc0 + be[cc], 0.0f);
            float o1 = fmaxf((acc[j * 2 + 1] + bias[cc + 1] - mn[cc + 1]) * sc1 + be[cc + 1], 0.0f);
            r[j] = (uint)f2bf(o0) | ((uint)f2bf(o1) << 16);
        }
        uint4 rv = {r[0], r[1], r[2], r[3]};
        *(uint4*)&out[(size_t)node * 128 + c] = rv;
    }
}

// ============ MFMA GEMM: Y = X(n,128) @ W(128,128), fused epilogues ============
// MODE 0: raw -> bf16   MODE 1: relu(bn(v+bias)) -> bf16
// MODE 2: relu(v+bias) -> f32, PLUS fused head: pred = softplus(h1 @ Wo + bo)
template <int MODE>
__global__ __launch_bounds__(256) void mfma_gemm_k(const ushort* __restrict__ Xb,
                                                   const ushort* __restrict__ Wt,
                                                   const float* __restrict__ bias,
                                                   const float* __restrict__ g,
                                                   const float* __restrict__ be,
                                                   const float* __restrict__ mn,
                                                   const float* __restrict__ vr,
                                                   const float* __restrict__ Wo,
                                                   const float* __restrict__ bo,
                                                   float* __restrict__ pred,
                                                   void* __restrict__ Y, int nrows) {
    constexpr int LDK = 136;  // 128 + 8 pad
    __shared__ ushort sX[64 * LDK];
    __shared__ ushort sW[128 * LDK];
    __shared__ float red[64];
    const int tid = threadIdx.x;
    const int row0 = blockIdx.x * 64;

#pragma unroll
    for (int i = 0; i < 8; i++) {
        int c = tid + i * 256;
        int r = c >> 4, o = c & 15;
        *(int4*)&sW[r * LDK + o * 8] = *(const int4*)&Wt[r * 128 + o * 8];
    }
#pragma unroll
    for (int i = 0; i < 4; i++) {
        int c = tid + i * 256;
        int r = c >> 4, o = c & 15;
        int rg = row0 + r;
        if (rg >= nrows) rg = nrows - 1;
        *(int4*)&sX[r * LDK + o * 8] = *(const int4*)&Xb[(size_t)rg * 128 + o * 8];
    }
    if (MODE == 2 && tid < 64) red[tid] = 0.0f;
    __syncthreads();

    const int wave = tid >> 6, lane = tid & 63;
    const int rw = (wave >> 1) * 32;
    const int cw = (wave & 1) * 64;
    const int lm = lane & 15, lq = lane >> 4;

    f32x4 acc[2][4];
#pragma unroll
    for (int tr = 0; tr < 2; tr++)
#pragma unroll
        for (int tc = 0; tc < 4; tc++) acc[tr][tc] = (f32x4){0.f, 0.f, 0.f, 0.f};

#pragma unroll
    for (int ks = 0; ks < 4; ks++) {
        int kb = ks * 32 + lq * 8;
        bf16x8 a[2], b[4];
#pragma unroll
        for (int tr = 0; tr < 2; tr++)
            a[tr] = *(bf16x8*)&sX[(rw + tr * 16 + lm) * LDK + kb];
#pragma unroll
        for (int tc = 0; tc < 4; tc++)
            b[tc] = *(bf16x8*)&sW[(cw + tc * 16 + lm) * LDK + kb];
#pragma unroll
        for (int tr = 0; tr < 2; tr++)
#pragma unroll
            for (int tc = 0; tc < 4; tc++)
                acc[tr][tc] = __builtin_amdgcn_mfma_f32_16x16x32_bf16(a[tr], b[tc],
                                                                      acc[tr][tc], 0, 0, 0);
    }

    float part[8];
    if (MODE == 2) {
#pragma unroll
        for (int i = 0; i < 8; i++) part[i] = 0.0f;
    }
#pragma unroll
    for (int tc = 0; tc < 4; tc++) {
        int c = cw + tc * 16 + lm;
        float psc, psh;
        if (MODE == 1) {
            float sc = g[c] * rsqrtf(vr[c] + EPS_BN);
            psc = sc;
            psh = be[c] + (bias[c] - mn[c]) * sc;
        } else if (MODE == 2) {
            psc = 1.0f;
            psh = bias[c];
        } else {
            psc = 1.0f;
            psh = 0.0f;
        }
        float woc = (MODE == 2) ? Wo[c] : 0.0f;
#pragma unroll
        for (int tr = 0; tr < 2; tr++) {
#pragma unroll
            for (int r = 0; r < 4; r++) {
                int row = row0 + rw + tr * 16 + lq * 4 + r;
                if (row < nrows) {
                    float v = acc[tr][tc][r] * psc + psh;
                    if (MODE != 0) v = fmaxf(v, 0.0f);
                    if (MODE == 2) {
                        ((float*)Y)[(size_t)row * 128 + c] = v;
                        part[tr * 4 + r] = fmaf(v, woc, part[tr * 4 + r]);
                    } else {
                        ((ushort*)Y)[(size_t)row * 128 + c] = f2bf(v);
                    }
                }
            }
        }
    }
    if (MODE == 2) {
#pragma unroll
        for (int tr = 0; tr < 2; tr++)
#pragma unroll
            for (int r = 0; r < 4; r++)
                atomicAdd(&red[rw + tr * 16 + lq * 4 + r], part[tr * 4 + r]);
        __syncthreads();
        if (tid < 64) {
            int row = row0 + tid;
            if (row < nrows) {
                float xv = red[tid] + bo[0];
                pred[row] = fmaxf(xv, 0.0f) + log1pf(expf(-fabsf(xv)));  // softplus
            }
        }
    }
}

extern "C" void kernel_launch(void* const* d_in, const int* in_sizes, int n_in,
                              void* d_out, int out_size, void* d_ws, size_t ws_size,
                              hipStream_t stream) {
    const float* x = (const float*)d_in[0];
    const int* ei = (const int*)d_in[1];
    const int N = in_sizes[0] / 128;
    const int E = in_sizes[1] / 2;
    const int* srcv = ei;
    const int* dstv = ei + E;
    const float* W1 = (const float*)d_in[2];  const float* b1 = (const float*)d_in[3];
    const float* W2 = (const float*)d_in[4];  const float* b2 = (const float*)d_in[5];
    const float* Wf1 = (const float*)d_in[6]; const float* bf1 = (const float*)d_in[7];
    const float* Wf2 = (const float*)d_in[8]; const float* bf2 = (const float*)d_in[9];
    const float* Wo = (const float*)d_in[10]; const float* bo = (const float*)d_in[11];
    const float* g1 = (const float*)d_in[12], *be1 = (const float*)d_in[13],
               *m1 = (const float*)d_in[14], *v1 = (const float*)d_in[15];
    const float* g2 = (const float*)d_in[16], *be2 = (const float*)d_in[17],
               *m2 = (const float*)d_in[18], *v2 = (const float*)d_in[19];
    const float* g3 = (const float*)d_in[20], *be3 = (const float*)d_in[21],
               *m3 = (const float*)d_in[22], *v3 = (const float*)d_in[23];

    // ---- workspace carve-up ----
    char* ws = (char*)d_ws;
    size_t off = 0;
    auto carve = [&](size_t bytes) {
        char* p = ws + off;
        off = (off + bytes + 255) & ~(size_t)255;
        return p;
    };
    const int NB = (N + 255) >> 8;
    int* bcnt = (int*)carve((size_t)MAXNB * 4);
    int* bstart = (int*)carve((size_t)(MAXNB + 1) * 4);
    int* bcur = (int*)carve((size_t)MAXNB * 4);
    int* rowstart = (int*)carve((size_t)(N + 1) * 4);
    int* col = (int*)carve((size_t)E * 4);
    int* coarse = (int*)carve((size_t)E * 4);
    float* dinv = (float*)carve((size_t)N * 4);
    ushort* XB = (ushort*)carve((size_t)N * 128 * 2);
    ushort* bufA = (ushort*)carve((size_t)N * 128 * 2);
    ushort* bufB = (ushort*)carve((size_t)N * 128 * 2);
    ushort* Wt1 = (ushort*)carve(128 * 128 * 2);
    ushort* Wt2 = (ushort*)carve(128 * 128 * 2);
    ushort* Wtf1 = (ushort*)carve(128 * 128 * 2);
    ushort* Wtf2 = (ushort*)carve(128 * 128 * 2);

    float* out_pred = (float*)d_out;
    float* out_h1 = out_pred + N;

    const int gblocks = (N + 63) / 64;
    const int tblocks = (E + 4095) / 4096;
    const int wblocks = (N + 3) / 4;
    const int cblocks = (int)(((size_t)N * 128 / 4 + 255) / 256);

    // ---- bucketed CSR build ----
    hipMemsetAsync(bcnt, 0, (size_t)MAXNB * 4, stream);
    chist_k<<<tblocks, 256, 0, stream>>>(dstv, bcnt, E, NB);
    cscan_k<<<1, 512, 0, stream>>>(bcnt, bstart, bcur, rowstart, NB, E, N);
    bucketA_k<<<tblocks, 256, 0, stream>>>(srcv, dstv, bcur, coarse, E, NB);
    bucketB_k<<<NB, 256, 0, stream>>>(coarse, bstart, rowstart, col, dinv, N);

    // ---- dtype prep ----
    cvt_bf16_k<<<cblocks, 256, 0, stream>>>(x, XB, N * 128 / 4);
    prep_wt_all_k<<<256, 256, 0, stream>>>(W1, W2, Wf1, Wf2, Wt1, Wt2, Wtf1, Wtf2);

    // layer 1: h = relu(bn1(conv(x@W1) + b1))
    mfma_gemm_k<0><<<gblocks, 256, 0, stream>>>(XB, Wt1, nullptr, nullptr, nullptr,
                                                nullptr, nullptr, nullptr, nullptr,
                                                nullptr, bufA, N);
    gather_k<<<wblocks, 256, 0, stream>>>(bufA, rowstart, col, dinv, b1, g1, be1, m1, v1,
                                          bufB, N);

    // layer 2: h = relu(bn2(conv(h@W2) + b2))
    mfma_gemm_k<0><<<gblocks, 256, 0, stream>>>(bufB, Wt2, nullptr, nullptr, nullptr,
                                                nullptr, nullptr, nullptr, nullptr,
                                                nullptr, bufA, N);
    gather_k<<<wblocks, 256, 0, stream>>>(bufA, rowstart, col, dinv, b2, g2, be2, m2, v2,
                                          bufB, N);

    // layer 3: h = relu(bn3(h@Wf1 + bf1))
    mfma_gemm_k<1><<<gblocks, 256, 0, stream>>>(bufB, Wtf1, bf1, g3, be3, m3, v3,
                                                nullptr, nullptr, nullptr, bufA, N);

    // layer 4 + head: h1 = relu(h@Wf2 + bf2) -> f32 d_out; pred = softplus(h1@Wo+bo)
    mfma_gemm_k<2><<<gblocks, 256, 0, stream>>>(bufA, Wtf2, bf2, nullptr, nullptr,
                                                nullptr, nullptr, Wo, bo, out_pred,
                                                out_h1, N);
}